// Round 3
// baseline (483.359 us; speedup 1.0000x reference)
//
#include <hip/hip_runtime.h>

#define NN 20000
#define NPAD 20064  // padded to BM=64 multiple

typedef _Float16 half8 __attribute__((ext_vector_type(8)));
typedef float floatx4 __attribute__((ext_vector_type(4)));

// ---------------- B-spline basis (grid [-1,1], G=4, order 3, NB=7) ----------------
__device__ __forceinline__ void bspline7(float x, float b[7]) {
  float t[10];
#pragma unroll
  for (int i = 0; i < 10; ++i) {
    float g = -2.5f + 0.5f * (float)i;
    t[i] = (x >= g && x < g + 0.5f) ? 1.0f : 0.0f;
  }
#pragma unroll
  for (int i = 0; i < 9; ++i) {  // k=1, denom 0.5
    float g = -2.5f + 0.5f * (float)i;
    t[i] = ((x - g) * t[i] + (g + 1.0f - x) * t[i + 1]) * 2.0f;
  }
#pragma unroll
  for (int i = 0; i < 8; ++i) {  // k=2, denom 1.0
    float g = -2.5f + 0.5f * (float)i;
    t[i] = ((x - g) * t[i] + (g + 1.5f - x) * t[i + 1]);
  }
#pragma unroll
  for (int i = 0; i < 7; ++i) {  // k=3, denom 1.5
    float g = -2.5f + 0.5f * (float)i;
    b[i] = ((x - g) * t[i] + (g + 2.0f - x) * t[i + 1]) * (1.0f / 1.5f);
  }
}

__device__ __forceinline__ float silu_f(float x) {
  return x * (1.0f / (1.0f + __expf(-x)));
}

// ---------------- feature build: X (f32 row-major) -> F fp16 [row][i][j=0..7] ----------------
// j=0: silu(x), j=1..7: spline basis. Optional BN applied inline (x' = x*ss[c]+ss[128+c]).
__global__ void fb_kernel(const float* __restrict__ X, const float* __restrict__ ss,
                          _Float16* __restrict__ F, int has_bn) {
  int idx = blockIdx.x * 256 + threadIdx.x;  // NN*128 = 2,560,000
  if (idx >= NN * 128) return;
  int c = idx & 127;
  float x = X[idx];
  if (has_bn) x = x * ss[c] + ss[128 + c];
  float b[7];
  bspline7(x, b);
  half8 hv;
  hv[0] = (_Float16)silu_f(x);
#pragma unroll
  for (int k = 0; k < 7; ++k) hv[k + 1] = (_Float16)b[k];
  *(half8*)(F + (size_t)idx * 8) = hv;
}

// ---------------- weight packs (MFMA B-fragment order) ----------------
// WP[ks][cb][lane][jj]: value W[k][o], k = ks*32 + (lane>>4)*8 + jj (k interleaved i*8+j),
// o = cb*16 + (lane&15). cb<8: layer weights (128 outs). cb>=8: out-layer chunk s (64 cols, 40 real).
__global__ void packwA(const float* __restrict__ Wb, const float* __restrict__ Ws,
                       const float* __restrict__ WbO, const float* __restrict__ WsO,
                       int s, _Float16* __restrict__ WP) {
  int idx = blockIdx.x * 256 + threadIdx.x;  // 32*12*64*8 = 196608
  if (idx >= 196608) return;
  int jj = idx & 7;
  int lane = (idx >> 3) & 63;
  int u = idx >> 9;  // ks*12 + cb
  int cb = u % 12, ks = u / 12;
  int i = ks * 4 + (lane >> 4);
  int orow = lane & 15;
  float v = 0.0f;
  if (cb < 8) {
    int o = cb * 16 + orow;
    v = (jj == 0) ? Wb[(size_t)o * 128 + i] : Ws[(size_t)o * 896 + i * 7 + (jj - 1)];
  } else {
    int o = (cb - 8) * 16 + orow;
    if (o < 40)
      v = (jj == 0) ? WbO[(size_t)o * 384 + s * 128 + i]
                    : WsO[(size_t)o * 2688 + s * 896 + i * 7 + (jj - 1)];
  }
  WP[idx] = (_Float16)v;
}

// out-layer chunk 2 only: 64 cols
__global__ void packwC(const float* __restrict__ WbO, const float* __restrict__ WsO,
                       _Float16* __restrict__ WP) {
  int idx = blockIdx.x * 256 + threadIdx.x;  // 32*4*64*8 = 65536
  if (idx >= 65536) return;
  int jj = idx & 7;
  int lane = (idx >> 3) & 63;
  int u = idx >> 9;
  int cb = u & 3, ks = u >> 2;
  int i = ks * 4 + (lane >> 4);
  int o = cb * 16 + (lane & 15);
  float v = 0.0f;
  if (o < 40)
    v = (jj == 0) ? WbO[(size_t)o * 384 + 2 * 128 + i]
                  : WsO[(size_t)o * 2688 + 2 * 896 + i * 7 + (jj - 1)];
  WP[idx] = (_Float16)v;
}

// ---------------- graph meta ----------------
__global__ void count_deg(const int* __restrict__ dst, int* __restrict__ degE, int E) {
  int e = blockIdx.x * 256 + threadIdx.x;
  if (e < E) atomicAdd(&degE[dst[e]], 1);
}

__global__ void build_meta(const int* __restrict__ degE, int* __restrict__ rowptr,
                           int* __restrict__ cursor, float* __restrict__ dinv, int n) {
  __shared__ int wsum[16];
  __shared__ int carrySh;
  int tid = threadIdx.x, lane = tid & 63, wid = tid >> 6;
  if (tid == 0) { carrySh = 0; rowptr[0] = 0; }
  __syncthreads();
  for (int base = 0; base < n; base += 1024) {
    int i = base + tid;
    int v = (i < n) ? degE[i] : 0;
    if (i < n) dinv[i] = rsqrtf((float)(v + 1));  // +1 self loop
    int val = v;
#pragma unroll
    for (int off = 1; off < 64; off <<= 1) {
      int t = __shfl_up(val, off);
      if (lane >= off) val += t;
    }
    if (lane == 63) wsum[wid] = val;
    __syncthreads();
    if (wid == 0) {
      int wv = (lane < 16) ? wsum[lane] : 0;
#pragma unroll
      for (int off = 1; off < 16; off <<= 1) {
        int t = __shfl_up(wv, off);
        if (lane >= off) wv += t;
      }
      if (lane < 16) wsum[lane] = wv;
    }
    __syncthreads();
    int wbase = wid ? wsum[wid - 1] : 0;
    int incl = wbase + val;
    int c = carrySh;
    if (i < n) {
      rowptr[i + 1] = c + incl;
      cursor[i] = c + incl - v;
    }
    __syncthreads();
    if (tid == 1023) carrySh = c + wsum[15];
    __syncthreads();
  }
}

__global__ void fill_csr(const int* __restrict__ src, const int* __restrict__ dst,
                         int* __restrict__ cursor, int* __restrict__ csr, int E) {
  int e = blockIdx.x * 256 + threadIdx.x;
  if (e < E) {
    int p = atomicAdd(&cursor[dst[e]], 1);
    csr[p] = src[e];
  }
}

// ---------------- GEMM: F(K=1024) x [W_layer(128) | W_out_chunk(64)] ----------------
// wave = 16 rows x 192 cols, block = 4 waves (BM=64), no LDS.
__global__ __launch_bounds__(256) void gemmA(const _Float16* __restrict__ F,
                                             const _Float16* __restrict__ WP,
                                             float* __restrict__ A, float* __restrict__ P) {
  int lane = threadIdx.x & 63, wid = threadIdx.x >> 6;
  int row0 = blockIdx.x * 64 + wid * 16;
  const _Float16* Fr = F + ((size_t)(row0 + (lane & 15)) * 128 + (lane >> 4)) * 8;
  floatx4 acc[12] = {};
#pragma unroll 2
  for (int ks = 0; ks < 32; ++ks) {
    half8 a = *(const half8*)(Fr + (size_t)ks * 32);
    const _Float16* bp = WP + ((size_t)ks * 12 * 64 + lane) * 8;
#pragma unroll
    for (int q = 0; q < 12; ++q) {
      half8 b = *(const half8*)(bp + (size_t)q * 64 * 8);
      acc[q] = __builtin_amdgcn_mfma_f32_16x16x32_f16(a, b, acc[q], 0, 0, 0);
    }
  }
  int r0 = row0 + (lane >> 4) * 4, oc = lane & 15;
#pragma unroll
  for (int q = 0; q < 8; ++q)
#pragma unroll
    for (int t = 0; t < 4; ++t) A[(size_t)(r0 + t) * 128 + q * 16 + oc] = acc[q][t];
#pragma unroll
  for (int q = 0; q < 4; ++q)
#pragma unroll
    for (int t = 0; t < 4; ++t) P[(size_t)(r0 + t) * 64 + q * 16 + oc] = acc[8 + q][t];
}

// final chunk: F(h2 feats) x W_out_chunk2 (64 cols) + P0 + P1 -> C (in-place over P0 is safe)
__global__ __launch_bounds__(256) void gemmC(const _Float16* __restrict__ F,
                                             const _Float16* __restrict__ WP,
                                             const float* __restrict__ P0,
                                             const float* __restrict__ P1,
                                             float* __restrict__ C) {
  int lane = threadIdx.x & 63, wid = threadIdx.x >> 6;
  int row0 = blockIdx.x * 64 + wid * 16;
  const _Float16* Fr = F + ((size_t)(row0 + (lane & 15)) * 128 + (lane >> 4)) * 8;
  floatx4 acc[4] = {};
#pragma unroll 2
  for (int ks = 0; ks < 32; ++ks) {
    half8 a = *(const half8*)(Fr + (size_t)ks * 32);
    const _Float16* bp = WP + ((size_t)ks * 4 * 64 + lane) * 8;
#pragma unroll
    for (int q = 0; q < 4; ++q) {
      half8 b = *(const half8*)(bp + (size_t)q * 64 * 8);
      acc[q] = __builtin_amdgcn_mfma_f32_16x16x32_f16(a, b, acc[q], 0, 0, 0);
    }
  }
  int r0 = row0 + (lane >> 4) * 4, oc = lane & 15;
#pragma unroll
  for (int q = 0; q < 4; ++q)
#pragma unroll
    for (int t = 0; t < 4; ++t) {
      size_t idx = (size_t)(r0 + t) * 64 + q * 16 + oc;
      C[idx] = acc[q][t] + P0[idx] + P1[idx];
    }
}

// ---------------- aggregation ----------------
__global__ void aggregate128(const float* __restrict__ H, const int* __restrict__ rowptr,
                             const int* __restrict__ csr, const float* __restrict__ dinv,
                             const float* __restrict__ bias, float* __restrict__ Y) {
  int n = blockIdx.x;
  int f = threadIdx.x;  // 128
  float di = dinv[n];
  float acc = H[(size_t)n * 128 + f] * di;
  int e0 = rowptr[n], e1 = rowptr[n + 1];
  for (int e = e0; e < e1; ++e) {
    int s = csr[e];
    acc += H[(size_t)s * 128 + f] * dinv[s];
  }
  Y[(size_t)n * 128 + f] = acc * di + bias[f];
}

__global__ void aggregate40(const float* __restrict__ C, const int* __restrict__ rowptr,
                            const int* __restrict__ csr, const float* __restrict__ dinv,
                            const float* __restrict__ bias, float* __restrict__ out) {
  int n = blockIdx.x;
  int f = threadIdx.x;  // 64 threads, 40 real (pad cols are exact zeros)
  float di = dinv[n];
  float acc = C[(size_t)n * 64 + f] * di;
  int e0 = rowptr[n], e1 = rowptr[n + 1];
  for (int e = e0; e < e1; ++e) {
    int s = csr[e];
    acc += C[(size_t)s * 64 + f] * dinv[s];
  }
  if (f < 40) out[(size_t)n * 40 + f] = acc * di + bias[f];
}

// ---------------- batchnorm stats ----------------
__global__ void bn_stats(const float* __restrict__ H, double* __restrict__ stats) {
  int tid = threadIdx.x;  // 256
  int col = tid & 127;
  double s = 0.0, s2 = 0.0;
  for (size_t idx = blockIdx.x * 256 + tid; idx < (size_t)NN * 128; idx += (size_t)gridDim.x * 256) {
    float v = H[idx];
    s += v;
    s2 += (double)v * (double)v;
  }
  __shared__ double sh[512];
  sh[tid] = s;
  sh[tid + 256] = s2;
  __syncthreads();
  if (tid < 128) {
    atomicAdd(&stats[col], sh[tid] + sh[tid + 128]);
    atomicAdd(&stats[128 + col], sh[tid + 256] + sh[tid + 384]);
  }
}

__global__ void bn_final(const double* __restrict__ stats, const float* __restrict__ gamma,
                         const float* __restrict__ beta, float* __restrict__ ss) {
  int c = threadIdx.x;  // 128
  double mean = stats[c] / (double)NN;
  double var = stats[128 + c] / (double)NN - mean * mean;
  float sc = gamma[c] * rsqrtf((float)var + 1e-5f);
  ss[c] = sc;
  ss[128 + c] = beta[c] - (float)mean * sc;
}

// ---------------- launch ----------------
extern "C" void kernel_launch(void* const* d_in, const int* in_sizes, int n_in,
                              void* d_out, int out_size, void* d_ws, size_t ws_size,
                              hipStream_t stream) {
  const float* x = (const float*)d_in[0];
  const int* ei = (const int*)d_in[1];
  const float* bw0 = (const float*)d_in[2];
  const float* sw0 = (const float*)d_in[3];
  const float* b0 = (const float*)d_in[4];
  const float* bw1 = (const float*)d_in[5];
  const float* sw1 = (const float*)d_in[6];
  const float* b1 = (const float*)d_in[7];
  const float* bwo = (const float*)d_in[8];
  const float* swo = (const float*)d_in[9];
  const float* bo = (const float*)d_in[10];
  const float* gamma = (const float*)d_in[11];
  const float* beta = (const float*)d_in[12];
  const int E = in_sizes[1] / 2;
  const int* esrc = ei;
  const int* edst = ei + E;

  char* ws = (char*)d_ws;
  size_t off = 0;
  auto alloc = [&](size_t bytes) -> void* {
    void* p = ws + off;
    off = (off + bytes + 255) & ~(size_t)255;
    return p;
  };
  _Float16* WPA0 = (_Float16*)alloc(196608 * 2);
  _Float16* WPA1 = (_Float16*)alloc(196608 * 2);
  _Float16* WPC = (_Float16*)alloc(65536 * 2);
  float* dinv = (float*)alloc(NN * 4);
  int* degE = (int*)alloc(NN * 4);
  int* rowptr = (int*)alloc((NN + 1) * 4);
  int* cursor = (int*)alloc(NN * 4);
  int* csr = (int*)alloc((size_t)E * 4);
  _Float16* F = (_Float16*)alloc((size_t)NPAD * 1024 * 2);  // 41 MB, reused for all 3 sources
  float* A = (float*)alloc((size_t)NPAD * 128 * 4);
  float* h1 = (float*)alloc((size_t)NN * 128 * 4);  // h2 aliases h1 (h1 dead after fb)
  float* P0 = (float*)alloc((size_t)NPAD * 64 * 4);
  float* P1 = (float*)alloc((size_t)NPAD * 64 * 4);
  double* stats = (double*)alloc(256 * 8);
  float* ssb = (float*)alloc(256 * 4);
  float* h2 = h1;
  float* C3 = P0;  // gemmC in-place over P0 (per-element read-then-write)
  (void)ws_size; (void)n_in; (void)out_size;

  int egrid = (E + 255) / 256;
  int ggrid = NPAD / 64;  // 313... NPAD=20064 -> 313.5? ensure divisible
  // NPAD = 20064 = 64*313.5 -> fix: use 20096
  (void)ggrid;

  hipMemsetAsync(degE, 0, NN * sizeof(int), stream);
  packwA<<<768, 256, 0, stream>>>(bw0, sw0, bwo, swo, 0, WPA0);
  packwA<<<768, 256, 0, stream>>>(bw1, sw1, bwo, swo, 1, WPA1);
  packwC<<<256, 256, 0, stream>>>(bwo, swo, WPC);
  count_deg<<<egrid, 256, 0, stream>>>(edst, degE, E);
  build_meta<<<1, 1024, 0, stream>>>(degE, rowptr, cursor, dinv, NN);
  fill_csr<<<egrid, 256, 0, stream>>>(esrc, edst, cursor, csr, E);

  const int GG = 313;  // 313*64 = 20032 <= NPAD rows allocated

  // layer 0 (+ out chunk 0)
  fb_kernel<<<10000, 256, 0, stream>>>(x, ssb, F, 0);
  gemmA<<<GG, 256, 0, stream>>>(F, WPA0, A, P0);
  aggregate128<<<NN, 128, 0, stream>>>(A, rowptr, csr, dinv, b0, h1);
  hipMemsetAsync(stats, 0, 256 * sizeof(double), stream);
  bn_stats<<<128, 256, 0, stream>>>(h1, stats);
  bn_final<<<1, 128, 0, stream>>>(stats, gamma, beta, ssb);

  // layer 1 (+ out chunk 1)
  fb_kernel<<<10000, 256, 0, stream>>>(h1, ssb, F, 1);
  gemmA<<<GG, 256, 0, stream>>>(F, WPA1, A, P1);
  aggregate128<<<NN, 128, 0, stream>>>(A, rowptr, csr, dinv, b1, h2);
  hipMemsetAsync(stats, 0, 256 * sizeof(double), stream);
  bn_stats<<<128, 256, 0, stream>>>(h2, stats);
  bn_final<<<1, 128, 0, stream>>>(stats, gamma, beta, ssb);

  // out chunk 2 + combine, then aggregate
  fb_kernel<<<10000, 256, 0, stream>>>(h2, ssb, F, 1);
  gemmC<<<GG, 256, 0, stream>>>(F, WPC, P0, P1, C3);
  aggregate40<<<NN, 64, 0, stream>>>(C3, rowptr, csr, dinv, bo, (float*)d_out);
}

// Round 4
// 383.985 us; speedup vs baseline: 1.2588x; 1.2588x over previous
//
#include <hip/hip_runtime.h>

#define NN 20000
#define NPAD 20064  // >= 626*32 = 20032 rows covered by GEMM grid

typedef _Float16 half8 __attribute__((ext_vector_type(8)));
typedef float floatx4 __attribute__((ext_vector_type(4)));

// ---------------- B-spline basis (grid [-1,1], G=4, order 3, NB=7) ----------------
__device__ __forceinline__ void bspline7(float x, float b[7]) {
  float t[10];
#pragma unroll
  for (int i = 0; i < 10; ++i) {
    float g = -2.5f + 0.5f * (float)i;
    t[i] = (x >= g && x < g + 0.5f) ? 1.0f : 0.0f;
  }
#pragma unroll
  for (int i = 0; i < 9; ++i) {  // k=1, denom 0.5
    float g = -2.5f + 0.5f * (float)i;
    t[i] = ((x - g) * t[i] + (g + 1.0f - x) * t[i + 1]) * 2.0f;
  }
#pragma unroll
  for (int i = 0; i < 8; ++i) {  // k=2, denom 1.0
    float g = -2.5f + 0.5f * (float)i;
    t[i] = ((x - g) * t[i] + (g + 1.5f - x) * t[i + 1]);
  }
#pragma unroll
  for (int i = 0; i < 7; ++i) {  // k=3, denom 1.5
    float g = -2.5f + 0.5f * (float)i;
    b[i] = ((x - g) * t[i] + (g + 2.0f - x) * t[i + 1]) * (1.0f / 1.5f);
  }
}

__device__ __forceinline__ float silu_f(float x) {
  return x * (1.0f / (1.0f + __expf(-x)));
}

// ---------------- feature build: X (f32 row-major) -> F fp16 [row][i][j=0..7] ----------------
__global__ void fb_kernel(const float* __restrict__ X, const float* __restrict__ ss,
                          _Float16* __restrict__ F, int has_bn) {
  int idx = blockIdx.x * 256 + threadIdx.x;  // NN*128 = 2,560,000
  if (idx >= NN * 128) return;
  int c = idx & 127;
  float x = X[idx];
  if (has_bn) x = x * ss[c] + ss[128 + c];
  float b[7];
  bspline7(x, b);
  half8 hv;
  hv[0] = (_Float16)silu_f(x);
#pragma unroll
  for (int k = 0; k < 7; ++k) hv[k + 1] = (_Float16)b[k];
  *(half8*)(F + (size_t)idx * 8) = hv;
}

// ---------------- weight packs (MFMA B-fragment order) ----------------
// WP[ks][cb][lane][jj]: W[k][o], k = ks*32 + (lane>>4)*8 + jj (k interleaved i*8+j),
// o = cb*16 + (lane&15). cb<8: layer weights. cb>=8: out-layer chunk s (64 cols, 40 real).
__global__ void packwA(const float* __restrict__ Wb, const float* __restrict__ Ws,
                       const float* __restrict__ WbO, const float* __restrict__ WsO,
                       int s, _Float16* __restrict__ WP) {
  int idx = blockIdx.x * 256 + threadIdx.x;  // 32*12*64*8 = 196608
  if (idx >= 196608) return;
  int jj = idx & 7;
  int lane = (idx >> 3) & 63;
  int u = idx >> 9;  // ks*12 + cb
  int cb = u % 12, ks = u / 12;
  int i = ks * 4 + (lane >> 4);
  int orow = lane & 15;
  float v = 0.0f;
  if (cb < 8) {
    int o = cb * 16 + orow;
    v = (jj == 0) ? Wb[(size_t)o * 128 + i] : Ws[(size_t)o * 896 + i * 7 + (jj - 1)];
  } else {
    int o = (cb - 8) * 16 + orow;
    if (o < 40)
      v = (jj == 0) ? WbO[(size_t)o * 384 + s * 128 + i]
                    : WsO[(size_t)o * 2688 + s * 896 + i * 7 + (jj - 1)];
  }
  WP[idx] = (_Float16)v;
}

__global__ void packwC(const float* __restrict__ WbO, const float* __restrict__ WsO,
                       _Float16* __restrict__ WP) {
  int idx = blockIdx.x * 256 + threadIdx.x;  // 32*4*64*8 = 65536
  if (idx >= 65536) return;
  int jj = idx & 7;
  int lane = (idx >> 3) & 63;
  int u = idx >> 9;
  int cb = u & 3, ks = u >> 2;
  int i = ks * 4 + (lane >> 4);
  int o = cb * 16 + (lane & 15);
  float v = 0.0f;
  if (o < 40)
    v = (jj == 0) ? WbO[(size_t)o * 384 + 2 * 128 + i]
                  : WsO[(size_t)o * 2688 + 2 * 896 + i * 7 + (jj - 1)];
  WP[idx] = (_Float16)v;
}

// ---------------- graph meta ----------------
__global__ void count_deg(const int* __restrict__ dst, int* __restrict__ degE, int E) {
  int e = blockIdx.x * 256 + threadIdx.x;
  if (e < E) atomicAdd(&degE[dst[e]], 1);
}

__global__ void build_meta(const int* __restrict__ degE, int* __restrict__ rowptr,
                           int* __restrict__ cursor, float* __restrict__ dinv, int n) {
  __shared__ int wsum[16];
  __shared__ int carrySh;
  int tid = threadIdx.x, lane = tid & 63, wid = tid >> 6;
  if (tid == 0) { carrySh = 0; rowptr[0] = 0; }
  __syncthreads();
  for (int base = 0; base < n; base += 1024) {
    int i = base + tid;
    int v = (i < n) ? degE[i] : 0;
    if (i < n) dinv[i] = rsqrtf((float)(v + 1));  // +1 self loop
    int val = v;
#pragma unroll
    for (int off = 1; off < 64; off <<= 1) {
      int t = __shfl_up(val, off);
      if (lane >= off) val += t;
    }
    if (lane == 63) wsum[wid] = val;
    __syncthreads();
    if (wid == 0) {
      int wv = (lane < 16) ? wsum[lane] : 0;
#pragma unroll
      for (int off = 1; off < 16; off <<= 1) {
        int t = __shfl_up(wv, off);
        if (lane >= off) wv += t;
      }
      if (lane < 16) wsum[lane] = wv;
    }
    __syncthreads();
    int wbase = wid ? wsum[wid - 1] : 0;
    int incl = wbase + val;
    int c = carrySh;
    if (i < n) {
      rowptr[i + 1] = c + incl;
      cursor[i] = c + incl - v;
    }
    __syncthreads();
    if (tid == 1023) carrySh = c + wsum[15];
    __syncthreads();
  }
}

__global__ void fill_csr(const int* __restrict__ src, const int* __restrict__ dst,
                         int* __restrict__ cursor, int* __restrict__ csr, int E) {
  int e = blockIdx.x * 256 + threadIdx.x;
  if (e < E) {
    int p = atomicAdd(&cursor[dst[e]], 1);
    csr[p] = src[e];
  }
}

// ---------------- GEMM A: F(K=1024) x [W_layer(128) | W_out_chunk(64)] ----------------
// 512 threads = 8 waves: rg = wid&1 (16-row group), cg = wid>>1 (3 col-fragments).
// Depth-1 register pipeline: loads for ks+1 issued before MFMA cluster of ks.
__global__ __launch_bounds__(512) void gemmA2(const _Float16* __restrict__ F,
                                              const _Float16* __restrict__ WP,
                                              float* __restrict__ A, float* __restrict__ P) {
  int lane = threadIdx.x & 63, wid = threadIdx.x >> 6;
  int rg = wid & 1, cg = wid >> 1;
  int row0 = blockIdx.x * 32 + rg * 16;
  const _Float16* Fr = F + ((size_t)(row0 + (lane & 15)) * 128 + (lane >> 4)) * 8;
  const _Float16* Bp = WP + ((size_t)(cg * 3) * 64 + lane) * 8;
  floatx4 acc0 = {}, acc1 = {}, acc2 = {};
  half8 a = *(const half8*)(Fr);
  half8 b0 = *(const half8*)(Bp);
  half8 b1 = *(const half8*)(Bp + 512);
  half8 b2 = *(const half8*)(Bp + 1024);
#pragma unroll 4
  for (int ks = 0; ks < 31; ++ks) {
    half8 an = *(const half8*)(Fr + (size_t)(ks + 1) * 32);
    const _Float16* bn = Bp + (size_t)(ks + 1) * 6144;
    half8 b0n = *(const half8*)(bn);
    half8 b1n = *(const half8*)(bn + 512);
    half8 b2n = *(const half8*)(bn + 1024);
    acc0 = __builtin_amdgcn_mfma_f32_16x16x32_f16(a, b0, acc0, 0, 0, 0);
    acc1 = __builtin_amdgcn_mfma_f32_16x16x32_f16(a, b1, acc1, 0, 0, 0);
    acc2 = __builtin_amdgcn_mfma_f32_16x16x32_f16(a, b2, acc2, 0, 0, 0);
    a = an; b0 = b0n; b1 = b1n; b2 = b2n;
  }
  acc0 = __builtin_amdgcn_mfma_f32_16x16x32_f16(a, b0, acc0, 0, 0, 0);
  acc1 = __builtin_amdgcn_mfma_f32_16x16x32_f16(a, b1, acc1, 0, 0, 0);
  acc2 = __builtin_amdgcn_mfma_f32_16x16x32_f16(a, b2, acc2, 0, 0, 0);
  int r0 = row0 + (lane >> 4) * 4, oc = lane & 15;
  floatx4 accs[3] = {acc0, acc1, acc2};
#pragma unroll
  for (int q = 0; q < 3; ++q) {
    int cb = cg * 3 + q;
    if (cb < 8) {
#pragma unroll
      for (int t = 0; t < 4; ++t) A[(size_t)(r0 + t) * 128 + cb * 16 + oc] = accs[q][t];
    } else {
#pragma unroll
      for (int t = 0; t < 4; ++t) P[(size_t)(r0 + t) * 64 + (cb - 8) * 16 + oc] = accs[q][t];
    }
  }
}

// final chunk: F(h2 feats) x W_out_chunk2 (64 cols) + P0 + P1 -> C
// 512 threads = 8 waves: rg = wid&1, cg = wid>>1 (1 col-fragment each).
__global__ __launch_bounds__(512) void gemmC2(const _Float16* __restrict__ F,
                                              const _Float16* __restrict__ WP,
                                              const float* __restrict__ P0,
                                              const float* __restrict__ P1,
                                              float* __restrict__ C) {
  int lane = threadIdx.x & 63, wid = threadIdx.x >> 6;
  int rg = wid & 1, cg = wid >> 1;
  int row0 = blockIdx.x * 32 + rg * 16;
  const _Float16* Fr = F + ((size_t)(row0 + (lane & 15)) * 128 + (lane >> 4)) * 8;
  const _Float16* Bp = WP + ((size_t)cg * 64 + lane) * 8;
  floatx4 acc = {};
  half8 a = *(const half8*)(Fr);
  half8 b = *(const half8*)(Bp);
#pragma unroll 4
  for (int ks = 0; ks < 31; ++ks) {
    half8 an = *(const half8*)(Fr + (size_t)(ks + 1) * 32);
    half8 bn = *(const half8*)(Bp + (size_t)(ks + 1) * 2048);
    acc = __builtin_amdgcn_mfma_f32_16x16x32_f16(a, b, acc, 0, 0, 0);
    a = an; b = bn;
  }
  acc = __builtin_amdgcn_mfma_f32_16x16x32_f16(a, b, acc, 0, 0, 0);
  int r0 = row0 + (lane >> 4) * 4, oc = lane & 15;
#pragma unroll
  for (int t = 0; t < 4; ++t) {
    size_t idx = (size_t)(r0 + t) * 64 + cg * 16 + oc;
    C[idx] = acc[t] + P0[idx] + P1[idx];
  }
}

// ---------------- aggregation (csr prefetch to break load chain) ----------------
__global__ void aggregate128(const float* __restrict__ H, const int* __restrict__ rowptr,
                             const int* __restrict__ csr, const float* __restrict__ dinv,
                             const float* __restrict__ bias, float* __restrict__ Y) {
  int n = blockIdx.x;
  int f = threadIdx.x;  // 128
  float di = dinv[n];
  float acc = H[(size_t)n * 128 + f] * di;
  int e0 = rowptr[n], e1 = rowptr[n + 1];
  int s = (e0 < e1) ? csr[e0] : 0;
  for (int e = e0; e < e1; ++e) {
    int sn = (e + 1 < e1) ? csr[e + 1] : 0;
    acc += H[(size_t)s * 128 + f] * dinv[s];
    s = sn;
  }
  Y[(size_t)n * 128 + f] = acc * di + bias[f];
}

__global__ void aggregate40(const float* __restrict__ C, const int* __restrict__ rowptr,
                            const int* __restrict__ csr, const float* __restrict__ dinv,
                            const float* __restrict__ bias, float* __restrict__ out) {
  int n = blockIdx.x;
  int f = threadIdx.x;  // 64 threads, 40 real (pad cols exact zero)
  float di = dinv[n];
  float acc = C[(size_t)n * 64 + f] * di;
  int e0 = rowptr[n], e1 = rowptr[n + 1];
  int s = (e0 < e1) ? csr[e0] : 0;
  for (int e = e0; e < e1; ++e) {
    int sn = (e + 1 < e1) ? csr[e + 1] : 0;
    acc += C[(size_t)s * 64 + f] * dinv[s];
    s = sn;
  }
  if (f < 40) out[(size_t)n * 40 + f] = acc * di + bias[f];
}

// ---------------- batchnorm stats ----------------
__global__ void bn_stats(const float* __restrict__ H, double* __restrict__ stats) {
  int tid = threadIdx.x;  // 256
  int col = tid & 127;
  double s = 0.0, s2 = 0.0;
  for (size_t idx = blockIdx.x * 256 + tid; idx < (size_t)NN * 128; idx += (size_t)gridDim.x * 256) {
    float v = H[idx];
    s += v;
    s2 += (double)v * (double)v;
  }
  __shared__ double sh[512];
  sh[tid] = s;
  sh[tid + 256] = s2;
  __syncthreads();
  if (tid < 128) {
    atomicAdd(&stats[col], sh[tid] + sh[tid + 128]);
    atomicAdd(&stats[128 + col], sh[tid + 256] + sh[tid + 384]);
  }
}

__global__ void bn_final(const double* __restrict__ stats, const float* __restrict__ gamma,
                         const float* __restrict__ beta, float* __restrict__ ss) {
  int c = threadIdx.x;  // 128
  double mean = stats[c] / (double)NN;
  double var = stats[128 + c] / (double)NN - mean * mean;
  float sc = gamma[c] * rsqrtf((float)var + 1e-5f);
  ss[c] = sc;
  ss[128 + c] = beta[c] - (float)mean * sc;
}

// ---------------- launch ----------------
extern "C" void kernel_launch(void* const* d_in, const int* in_sizes, int n_in,
                              void* d_out, int out_size, void* d_ws, size_t ws_size,
                              hipStream_t stream) {
  const float* x = (const float*)d_in[0];
  const int* ei = (const int*)d_in[1];
  const float* bw0 = (const float*)d_in[2];
  const float* sw0 = (const float*)d_in[3];
  const float* b0 = (const float*)d_in[4];
  const float* bw1 = (const float*)d_in[5];
  const float* sw1 = (const float*)d_in[6];
  const float* b1 = (const float*)d_in[7];
  const float* bwo = (const float*)d_in[8];
  const float* swo = (const float*)d_in[9];
  const float* bo = (const float*)d_in[10];
  const float* gamma = (const float*)d_in[11];
  const float* beta = (const float*)d_in[12];
  const int E = in_sizes[1] / 2;
  const int* esrc = ei;
  const int* edst = ei + E;

  char* ws = (char*)d_ws;
  size_t off = 0;
  auto alloc = [&](size_t bytes) -> void* {
    void* p = ws + off;
    off = (off + bytes + 255) & ~(size_t)255;
    return p;
  };
  _Float16* WPA0 = (_Float16*)alloc(196608 * 2);
  _Float16* WPA1 = (_Float16*)alloc(196608 * 2);
  _Float16* WPC = (_Float16*)alloc(65536 * 2);
  float* dinv = (float*)alloc(NN * 4);
  int* degE = (int*)alloc(NN * 4);
  int* rowptr = (int*)alloc((NN + 1) * 4);
  int* cursor = (int*)alloc(NN * 4);
  int* csr = (int*)alloc((size_t)E * 4);
  _Float16* F = (_Float16*)alloc((size_t)NPAD * 1024 * 2);  // 41 MB, reused for all 3 sources
  float* A = (float*)alloc((size_t)NPAD * 128 * 4);
  float* h1 = (float*)alloc((size_t)NN * 128 * 4);  // h2 aliases h1
  float* P0 = (float*)alloc((size_t)NPAD * 64 * 4);
  float* P1 = (float*)alloc((size_t)NPAD * 64 * 4);
  double* stats = (double*)alloc(256 * 8);
  float* ssb = (float*)alloc(256 * 4);
  float* h2 = h1;
  float* C3 = P0;  // gemmC2 in-place over P0 (one thread per element)
  (void)ws_size; (void)n_in; (void)out_size;

  int egrid = (E + 255) / 256;
  const int GG = 626;  // 626*32 = 20032 rows

  hipMemsetAsync(degE, 0, NN * sizeof(int), stream);
  packwA<<<768, 256, 0, stream>>>(bw0, sw0, bwo, swo, 0, WPA0);
  packwA<<<768, 256, 0, stream>>>(bw1, sw1, bwo, swo, 1, WPA1);
  packwC<<<256, 256, 0, stream>>>(bwo, swo, WPC);
  count_deg<<<egrid, 256, 0, stream>>>(edst, degE, E);
  build_meta<<<1, 1024, 0, stream>>>(degE, rowptr, cursor, dinv, NN);
  fill_csr<<<egrid, 256, 0, stream>>>(esrc, edst, cursor, csr, E);

  // layer 0 (+ out chunk 0)
  fb_kernel<<<10000, 256, 0, stream>>>(x, ssb, F, 0);
  gemmA2<<<GG, 512, 0, stream>>>(F, WPA0, A, P0);
  aggregate128<<<NN, 128, 0, stream>>>(A, rowptr, csr, dinv, b0, h1);
  hipMemsetAsync(stats, 0, 256 * sizeof(double), stream);
  bn_stats<<<128, 256, 0, stream>>>(h1, stats);
  bn_final<<<1, 128, 0, stream>>>(stats, gamma, beta, ssb);

  // layer 1 (+ out chunk 1)
  fb_kernel<<<10000, 256, 0, stream>>>(h1, ssb, F, 1);
  gemmA2<<<GG, 512, 0, stream>>>(F, WPA1, A, P1);
  aggregate128<<<NN, 128, 0, stream>>>(A, rowptr, csr, dinv, b1, h2);
  hipMemsetAsync(stats, 0, 256 * sizeof(double), stream);
  bn_stats<<<128, 256, 0, stream>>>(h2, stats);
  bn_final<<<1, 128, 0, stream>>>(stats, gamma, beta, ssb);

  // out chunk 2 + combine, then aggregate
  fb_kernel<<<10000, 256, 0, stream>>>(h2, ssb, F, 1);
  gemmC2<<<GG, 512, 0, stream>>>(F, WPC, P0, P1, C3);
  aggregate40<<<NN, 64, 0, stream>>>(C3, rowptr, csr, dinv, bo, (float*)d_out);
}